// Round 11
// baseline (726.727 us; speedup 1.0000x reference)
//
#include <hip/hip_runtime.h>
#include <cstdint>

#define N_N 100000
#define N_E 1600000
#define HID 128
#define N_G 100
#define EPSF 1e-5f

// edge partition parameters
#define NB   256                      // partition blocks
#define EPB  ((N_E + NB - 1) / NB)    // 6250 edges per block
#define NBKT ((N_N + 255) >> 8)       // 391 buckets of 256 nodes (dst >> 8)
#define NBB  ((N_N + 255) / 256)      // 391 boundary blocks
#define NWT  ((3 * HID * HID) / 256)  // 192 Wt blocks

// fused gstat parameters
#define GSB   (N_G * 8)               // 800 partial blocks
#define NFOLD 50                      // spinner blocks; 50*256 == N_G*HID

static inline int ceil_div(int a, int b){ return (a + b - 1) / b; }

typedef __attribute__((ext_vector_type(8))) short bf16x8;
typedef __attribute__((ext_vector_type(4))) float f32x4;

__device__ inline unsigned short f2bf(float f){
  unsigned int u = __float_as_uint(f);
  unsigned int r = u + 0x7fffu + ((u >> 16) & 1u);   // round-to-nearest-even
  return (unsigned short)(r >> 16);
}
// 8 packed bf16 (uint4) -> acc[0..7] += nv * val
__device__ inline void fma8(float* acc, float nv, uint4 u){
  acc[0] += nv * __uint_as_float(u.x << 16);
  acc[1] += nv * __uint_as_float(u.x & 0xffff0000u);
  acc[2] += nv * __uint_as_float(u.y << 16);
  acc[3] += nv * __uint_as_float(u.y & 0xffff0000u);
  acc[4] += nv * __uint_as_float(u.z << 16);
  acc[5] += nv * __uint_as_float(u.z & 0xffff0000u);
  acc[6] += nv * __uint_as_float(u.w << 16);
  acc[7] += nv * __uint_as_float(u.w & 0xffff0000u);
}

// ---- mega-pre: [0,NB) dst-histogram | [NB,NB+NBB) graph boundaries |
//      [NB+NBB, +NWT) W->bf16 transpose. All independent. Zeroes done[3].
__global__ __launch_bounds__(256) void k_pre(const int* __restrict__ dst,
                                             int* __restrict__ counts,
                                             const int* __restrict__ bp,
                                             int* __restrict__ gstart,
                                             int* __restrict__ gend,
                                             const float* __restrict__ W,
                                             unsigned short* __restrict__ Wt,
                                             int* __restrict__ done){
  int t = threadIdx.x, blk = blockIdx.x;
  if (blk == 0 && t < 3) done[t] = 0;
  if (blk < NB){
    __shared__ int h[NBKT];
    for (int i = t; i < NBKT; i += 256) h[i] = 0;
    __syncthreads();
    int e0 = blk * EPB, e1 = min(e0 + EPB, N_E);
    for (int e = e0 + t; e < e1; e += 256)
      atomicAdd(&h[dst[e] >> 8], 1);
    __syncthreads();
    for (int i = t; i < NBKT; i += 256) counts[i * NB + blk] = h[i];
  } else if (blk < NB + NBB){
    // boundary detect on sorted bp; gap-fills empty graph ids (no init pass)
    int i = (blk - NB) * 256 + t;
    if (i >= N_N) return;
    int g = bp[i];
    if (i == 0){
      gstart[g] = 0;
      for (int gg = 0; gg < g; ++gg){ gstart[gg] = 0; gend[gg] = 0; }
    } else {
      int pg = bp[i - 1];
      if (pg != g){
        gend[pg] = i; gstart[g] = i;
        for (int gg = pg + 1; gg < g; ++gg){ gstart[gg] = i; gend[gg] = i; }
      }
    }
    if (i == N_N - 1){
      gend[g] = N_N;
      for (int gg = g + 1; gg < N_G; ++gg){ gstart[gg] = N_N; gend[gg] = N_N; }
    }
  } else {
    int j = (blk - NB - NBB) * 256 + t;
    int l = j >> 14;            // 128*128 = 16384 per layer
    int r = j & 16383;
    int n = r >> 7, k = r & 127;
    Wt[j] = f2bf(W[l * HID * HID + k * HID + n]);
  }
}

// block-local exclusive scan; bsum gets RAW block totals (no scanB pass)
__global__ __launch_bounds__(256) void k_scanA(int* __restrict__ data,
                                               int* __restrict__ bsum, int n){
  __shared__ int s[256];
  int t = threadIdx.x;
  int i = blockIdx.x * 256 + t;
  int v = (i < n) ? data[i] : 0;
  s[t] = v; __syncthreads();
  #pragma unroll
  for (int off = 1; off < 256; off <<= 1){
    int tmp = (t >= off) ? s[t - off] : 0;
    __syncthreads();
    s[t] += tmp;
    __syncthreads();
  }
  if (i < n) data[i] = s[t] - v;
  if (t == 255) bsum[blockIdx.x] = s[255];
}

// Pass 2: partition edges into buckets. Scans the 391 raw bsum totals in LDS
// (replaces the scanB launch), then ranks via LDS atomics.
__global__ __launch_bounds__(256) void k_part(const int* __restrict__ src,
                                              const int* __restrict__ dst,
                                              const float* __restrict__ w,
                                              const int* __restrict__ coff,
                                              const int* __restrict__ bsum,
                                              int2* __restrict__ part){
  __shared__ int off[NBKT];
  __shared__ int sb[512];
  int t = threadIdx.x, blk = blockIdx.x;
  sb[t]       = (t < NBKT)       ? bsum[t]       : 0;
  sb[t + 256] = (t + 256 < NBKT) ? bsum[t + 256] : 0;
  __syncthreads();
  #pragma unroll
  for (int o = 1; o < 256; o <<= 1){
    int a  = (t >= o) ? sb[t - o] : 0;
    int b2 = (t >= o) ? sb[256 + t - o] : 0;
    __syncthreads();
    sb[t] += a; sb[256 + t] += b2;
    __syncthreads();
  }
  int tot0 = sb[255];
  sb[256 + t] += tot0;            // no hazard: upper writes don't touch sb[255]
  __syncthreads();                // sb[0..510] = inclusive scan of bsum
  for (int i = t; i < NBKT; i += 256)
    off[i] = coff[i * NB + blk] + (i == 0 ? 0 : sb[i - 1]);
  __syncthreads();
  int e0 = blk * EPB, e1 = min(e0 + EPB, N_E);
  for (int e = e0 + t; e < e1; e += 256){
    int d = dst[e];
    int pos = atomicAdd(&off[d >> 8], 1);
    part[pos] = make_int2(src[e] | ((d & 255) << 24), __float_as_int(w[e]));
  }
}

// Pass 3: per-bucket fine CSR. Computes its own bsum prefix S(b) by masked
// block-reduce. Weighted degree -> dis; writes ptr; PRE-MULTIPLIES edge
// weight by dis[dst]. (dis[src] is folded into Hb at gemm.)
__global__ __launch_bounds__(256) void k_csr(const int* __restrict__ coff,
                                             const int* __restrict__ bsum,
                                             const int2* __restrict__ part,
                                             int2* __restrict__ edge8,
                                             int* __restrict__ ptr,
                                             float* __restrict__ dis){
  __shared__ int h[256];
  __shared__ int c[256];
  __shared__ float wsum[256];
  __shared__ int s[256];
  int t = threadIdx.x, b = blockIdx.x;
  // S(b) = sum_{j<b} bsum[j] via masked reduce
  int acc = 0;
  if (t < b) acc += bsum[t];
  if (t + 256 < b) acc += bsum[t + 256];
  s[t] = acc; __syncthreads();
  #pragma unroll
  for (int o = 128; o >= 1; o >>= 1){
    if (t < o) s[t] += s[t + o];
    __syncthreads();
  }
  int Sb = s[0];
  int base  = coff[b * NB] + Sb;
  int base2 = (b + 1 < NBKT) ? coff[(b + 1) * NB] + Sb + bsum[b] : N_E;
  h[t] = 0; c[t] = 0; wsum[t] = 0.f;
  __syncthreads();
  for (int e = base + t; e < base2; e += 256){
    int2 v = part[e];
    int local = ((unsigned int)v.x) >> 24;
    atomicAdd(&h[local], 1);
    atomicAdd(&wsum[local], __int_as_float(v.y));
  }
  __syncthreads();
  // exclusive scan of h
  int v0 = h[t];
  s[t] = v0; __syncthreads();
  #pragma unroll
  for (int off = 1; off < 256; off <<= 1){
    int tmp = (t >= off) ? s[t - off] : 0;
    __syncthreads();
    s[t] += tmp;
    __syncthreads();
  }
  int mybase = base + s[t] - v0;
  int node = (b << 8) + t;
  float dv = rsqrtf(1.0f + wsum[t]);
  if (node < N_N){
    ptr[node] = mybase;
    dis[node] = dv;
  }
  if (b == NBKT - 1 && t == 0) ptr[N_N] = N_E;
  h[t] = mybase;              // repurpose h as scatter base (own slot only)
  __syncthreads();
  wsum[t] = dv;               // repurpose wsum as dis[dst] for the scatter
  __syncthreads();
  for (int e = base + t; e < base2; e += 256){
    int2 v = part[e];
    int local = ((unsigned int)v.x) >> 24;
    int pos = h[local] + atomicAdd(&c[local], 1);
    edge8[pos] = make_int2(v.x & 0x00ffffff,
                           __float_as_int(__int_as_float(v.y) * wsum[local]));
  }
}

// ---------------- GEMM via MFMA, optional fused GraphNorm+ReLU on input ------
// fused=0: A row = X[gr]. fused=1: A row = relu(gw*(agg-al*mean)*rstd+gb).
// Epilogue: rows scaled by dis[row] (folds old k_ne into Hb), C staged as
// bf16 in LDS (lA reused), coalesced uint4 stores.
__global__ __launch_bounds__(256) void k_gemm(const float* __restrict__ X,
                                              const float* __restrict__ agg,
                                              int fused,
                                              const int* __restrict__ bp,
                                              const float* __restrict__ mean,
                                              const float* __restrict__ rstd,
                                              const float* __restrict__ alpha,
                                              const float* __restrict__ gwv,
                                              const float* __restrict__ gbv,
                                              const unsigned short* __restrict__ Wt,
                                              const float* __restrict__ dis,
                                              unsigned short* __restrict__ Hb, int nrows){
  __shared__ unsigned short lA[64 * 136];
  __shared__ unsigned short lB[128 * 136];
  int tid = threadIdx.x;
  int row0 = blockIdx.x * 64;

  #pragma unroll
  for (int i = 0; i < 8; ++i){
    int c = tid + i * 256;
    int r = c >> 4, cc = c & 15;
    *(uint4*)&lB[r * 136 + cc * 8] = ((const uint4*)Wt)[c];
  }
  #pragma unroll
  for (int i = 0; i < 8; ++i){
    int c = tid + i * 256;
    int r = c >> 5, cc = c & 31;
    int gr = row0 + r;
    float4 v = make_float4(0.f, 0.f, 0.f, 0.f);
    if (gr < nrows){
      if (!fused){
        v = *(const float4*)(X + (size_t)gr * HID + cc * 4);
      } else {
        int g = bp[gr];
        float4 a  = *(const float4*)(agg  + (size_t)gr * HID + cc * 4);
        float4 m  = *(const float4*)(mean + g * HID + cc * 4);
        float4 rs = *(const float4*)(rstd + g * HID + cc * 4);
        float4 al = *(const float4*)(alpha + cc * 4);
        float4 wv = *(const float4*)(gwv + cc * 4);
        float4 bv = *(const float4*)(gbv + cc * 4);
        v.x = fmaxf(wv.x * (a.x - al.x * m.x) * rs.x + bv.x, 0.f);
        v.y = fmaxf(wv.y * (a.y - al.y * m.y) * rs.y + bv.y, 0.f);
        v.z = fmaxf(wv.z * (a.z - al.z * m.z) * rs.z + bv.z, 0.f);
        v.w = fmaxf(wv.w * (a.w - al.w * m.w) * rs.w + bv.w, 0.f);
      }
    }
    unsigned short pk[4] = {f2bf(v.x), f2bf(v.y), f2bf(v.z), f2bf(v.w)};
    *(uint2*)&lA[r * 136 + cc * 4] = *(const uint2*)pk;
  }
  __syncthreads();

  int wave = tid >> 6;
  int lane = tid & 63;
  int l16 = lane & 15;
  int quad = lane >> 4;
  int am = wave * 16 + l16;

  bf16x8 afr[4];
  #pragma unroll
  for (int kc = 0; kc < 4; ++kc)
    afr[kc] = *(const bf16x8*)&lA[am * 136 + kc * 32 + quad * 8];

  f32x4 accs[8];
  #pragma unroll
  for (int nt = 0; nt < 8; ++nt){
    f32x4 acc = {0.f, 0.f, 0.f, 0.f};
    int bn = nt * 16 + l16;
    #pragma unroll
    for (int kc = 0; kc < 4; ++kc){
      bf16x8 bfr = *(const bf16x8*)&lB[bn * 136 + kc * 32 + quad * 8];
      acc = __builtin_amdgcn_mfma_f32_16x16x32_bf16(afr[kc], bfr, acc, 0, 0, 0);
    }
    accs[nt] = acc;
  }

  int crow = wave * 16 + quad * 4;
  float ds[4];
  #pragma unroll
  for (int r = 0; r < 4; ++r){
    int grr = row0 + crow + r;
    ds[r] = (grr < nrows) ? dis[grr] : 0.f;
  }

  // all afr reads from lA are done (pre-loop, barrier-ordered) -> reuse lA for C
  __syncthreads();
  #pragma unroll
  for (int nt = 0; nt < 8; ++nt){
    int col = nt * 16 + l16;
    #pragma unroll
    for (int r = 0; r < 4; ++r)
      lA[(crow + r) * 136 + col] = f2bf(accs[nt][r] * ds[r]);
  }
  __syncthreads();
  #pragma unroll
  for (int i = 0; i < 4; ++i){
    int idx = i * 256 + tid;            // 0..1023 = 64 rows x 16 uint4
    int row = idx >> 4, c8 = idx & 15;
    int gr = row0 + row;
    if (gr < nrows)
      *(uint4*)&Hb[(size_t)gr * HID + c8 * 8] = *(const uint4*)&lA[row * 136 + c8 * 8];
  }
}

// ---- gather aggregation: 16 lanes/node, unroll x4 (plain, proven 65us form) --
// Hb rows pre-scaled by dis[src]; edge weight pre-scaled by dis[dst];
// self term multiplier = dis[node] (dis^2 * h_orig = dis * h_scaled).
__global__ __launch_bounds__(256) void k_gather(const int* __restrict__ ptr,
                                                const int2* __restrict__ edge8,
                                                const unsigned short* __restrict__ Hb,
                                                const float* __restrict__ dis,
                                                const float* __restrict__ bias,
                                                float* __restrict__ agg){
  int t = blockIdx.x * 256 + threadIdx.x;
  int node = t >> 4;
  if (node >= N_N) return;
  int lane = t & 15;                        // 8 features (16B) per lane
  const uint4* h16 = (const uint4*)Hb;      // 16 uint4 per row
  float ns = dis[node];
  uint4 hu = h16[(size_t)node * 16 + lane];
  float4 b0 = ((const float4*)bias)[lane * 2];
  float4 b1 = ((const float4*)bias)[lane * 2 + 1];
  float acc[8] = {b0.x, b0.y, b0.z, b0.w, b1.x, b1.y, b1.z, b1.w};
  fma8(acc, ns, hu);

  int e0 = ptr[node], e1 = ptr[node + 1];
  int e = e0;
  for (; e + 4 <= e1; e += 4){
    int2 ev0 = edge8[e + 0];
    int2 ev1 = edge8[e + 1];
    int2 ev2 = edge8[e + 2];
    int2 ev3 = edge8[e + 3];
    uint4 r0 = h16[(size_t)ev0.x * 16 + lane];
    uint4 r1 = h16[(size_t)ev1.x * 16 + lane];
    uint4 r2 = h16[(size_t)ev2.x * 16 + lane];
    uint4 r3 = h16[(size_t)ev3.x * 16 + lane];
    fma8(acc, __int_as_float(ev0.y), r0);
    fma8(acc, __int_as_float(ev1.y), r1);
    fma8(acc, __int_as_float(ev2.y), r2);
    fma8(acc, __int_as_float(ev3.y), r3);
  }
  for (; e < e1; ++e){
    int2 ev = edge8[e];
    uint4 r0 = h16[(size_t)ev.x * 16 + lane];
    fma8(acc, __int_as_float(ev.y), r0);
  }
  float4* ap = (float4*)(agg + (size_t)node * HID + lane * 8);
  ap[0] = make_float4(acc[0], acc[1], acc[2], acc[3]);
  ap[1] = make_float4(acc[4], acc[5], acc[6], acc[7]);
}

// ---- GraphNorm: fused two-phase reduction in ONE kernel (ticket + spinners) -
// 800 blocks write partials via agent-scope atomic stores (device-coherent,
// no cross-XCD staleness); last NFOLD=50 ticket holders spin on done==800,
// then each folds 256 of the 12800 mean/rstd elements.
__global__ __launch_bounds__(256) void k_gstat(const float* __restrict__ agg,
                                               const int* __restrict__ gstart,
                                               const int* __restrict__ gend,
                                               float* __restrict__ psum,
                                               float* __restrict__ psq,
                                               const float* __restrict__ alpha,
                                               float* __restrict__ mean,
                                               float* __restrict__ rstd,
                                               int* __restrict__ done){
  __shared__ float ls[256], lq[256];
  __shared__ int ticket;
  int g = blockIdx.x >> 3, c = blockIdx.x & 7;
  int s0 = gstart[g], e0 = gend[g];
  int len = e0 - s0;
  int r0 = s0 + ((len * c) >> 3);
  int r1 = s0 + ((len * (c + 1)) >> 3);
  int f = threadIdx.x & 127, rr = threadIdx.x >> 7;
  float sm = 0.f, sq = 0.f;
  for (int r = r0 + rr; r < r1; r += 2){
    float v = agg[(size_t)r * HID + f];
    sm += v; sq += v * v;
  }
  ls[threadIdx.x] = sm; lq[threadIdx.x] = sq;
  __syncthreads();
  if (rr == 0){
    __hip_atomic_store(&psum[(size_t)blockIdx.x * HID + f], ls[f] + ls[f + 128],
                       __ATOMIC_RELAXED, __HIP_MEMORY_SCOPE_AGENT);
    __hip_atomic_store(&psq [(size_t)blockIdx.x * HID + f], lq[f] + lq[f + 128],
                       __ATOMIC_RELAXED, __HIP_MEMORY_SCOPE_AGENT);
  }
  __threadfence();
  __syncthreads();
  if (threadIdx.x == 0) ticket = atomicAdd(done, 1);
  __syncthreads();
  int tk = ticket;
  if (tk < GSB - NFOLD) return;
  int slice = tk - (GSB - NFOLD);
  if (threadIdx.x == 0){
    while (atomicAdd(done, 0) < GSB) __builtin_amdgcn_s_sleep(8);
  }
  __syncthreads();
  __threadfence();
  int i = slice * 256 + threadIdx.x;          // [0, 12800) exactly
  int gg = i >> 7, ff = i & 127;
  float cnt = (float)(gend[gg] - gstart[gg]);
  float inv = cnt > 0.f ? 1.0f / cnt : 0.f;
  float fsm = 0.f, fsq = 0.f;
  #pragma unroll
  for (int k = 0; k < 8; ++k){
    fsm += __hip_atomic_load(&psum[(size_t)(gg * 8 + k) * HID + ff],
                             __ATOMIC_RELAXED, __HIP_MEMORY_SCOPE_AGENT);
    fsq += __hip_atomic_load(&psq [(size_t)(gg * 8 + k) * HID + ff],
                             __ATOMIC_RELAXED, __HIP_MEMORY_SCOPE_AGENT);
  }
  float m = fsm * inv;
  float ex2 = fsq * inv;
  float al = alpha[ff];
  float var = ex2 - m * m * al * (2.0f - al);
  mean[i] = m;
  rstd[i] = rsqrtf(var + EPSF);
}

__global__ void k_out(const float* __restrict__ agg, const int* __restrict__ bp,
                      const float* __restrict__ mean, const float* __restrict__ rstd,
                      const float* __restrict__ alpha, const float* __restrict__ gw,
                      const float* __restrict__ gb, float* __restrict__ out){
  int idx = blockIdx.x * 256 + threadIdx.x;
  if (idx >= N_N * 32) return;
  int i = idx >> 5, q = idx & 31;
  int g = bp[i];
  float4 a  = ((const float4*)agg)[idx];
  float4 m  = ((const float4*)mean)[g * 32 + q];
  float4 r  = ((const float4*)rstd)[g * 32 + q];
  float4 al = ((const float4*)alpha)[q];
  float4 wv = ((const float4*)gw)[q];
  float4 bv = ((const float4*)gb)[q];
  float4 o;
  o.x = fmaxf(wv.x * (a.x - al.x * m.x) * r.x + bv.x, 0.f);
  o.y = fmaxf(wv.y * (a.y - al.y * m.y) * r.y + bv.y, 0.f);
  o.z = fmaxf(wv.z * (a.z - al.z * m.z) * r.z + bv.z, 0.f);
  o.w = fmaxf(wv.w * (a.w - al.w * m.w) * r.w + bv.w, 0.f);
  ((float4*)out)[idx] = o;
}

// ---------------- launch ----------------

extern "C" void kernel_launch(void* const* d_in, const int* in_sizes, int n_in,
                              void* d_out, int out_size, void* d_ws, size_t ws_size,
                              hipStream_t stream){
  const float* node0 = (const float*)d_in[0];
  const int*   eidx  = (const int*)d_in[1];
  const float* eattr = (const float*)d_in[2];
  const int*   bp    = (const int*)d_in[3];
  const float* W     = (const float*)d_in[4];
  const float* bias  = (const float*)d_in[5];
  const float* gw    = (const float*)d_in[6];
  const float* gb    = (const float*)d_in[7];
  const float* ga    = (const float*)d_in[8];
  float* out = (float*)d_out;
  const int* src = eidx;
  const int* dst = eidx + N_E;

  char* p = (char*)d_ws;
  auto carve = [&](size_t nbytes) -> char* {
    char* q = p; p += (nbytes + 255) & ~(size_t)255; return q;
  };
  float* dis    = (float*)carve((size_t)N_N * 4);
  int*   gstart = (int*)  carve((size_t)N_G * 4);
  int*   gend   = (int*)  carve((size_t)N_G * 4);
  int*   coff   = (int*)  carve((size_t)NBKT * NB * 4);
  int*   bsum   = (int*)  carve((size_t)512 * 4);
  int*   done   = (int*)  carve((size_t)16 * 4);
  int*   ptr    = (int*)  carve((size_t)(N_N + 1) * 4);
  int2*  edge8  = (int2*) carve((size_t)N_E * 8);
  unsigned short* hb = (unsigned short*)carve((size_t)N_N * HID * 2);
  unsigned short* wt = (unsigned short*)carve((size_t)3 * HID * HID * 2);
  float* agg    = (float*)carve((size_t)N_N * HID * 4);
  float* mean   = (float*)carve((size_t)N_G * HID * 4);
  float* rstd   = (float*)carve((size_t)N_G * HID * 4);
  float* psum   = (float*)carve((size_t)GSB * HID * 4);
  float* psq    = (float*)carve((size_t)GSB * HID * 4);
  // bucket-partitioned edges alias agg (dead until first k_gather; 12.8MB < 51.2MB)
  int2*  part   = (int2*)agg;

  int nscan = NBKT * NB;                       // 100096
  int nscan_blocks = ceil_div(nscan, 256);     // 391 == NBKT

  k_pre  <<<NB + NBB + NWT, 256, 0, stream>>>(dst, coff, bp, gstart, gend, W, wt, done);
  k_scanA<<<nscan_blocks, 256, 0, stream>>>(coff, bsum, nscan);
  k_part <<<NB, 256, 0, stream>>>(src, dst, eattr, coff, bsum, part);
  k_csr  <<<NBKT, 256, 0, stream>>>(coff, bsum, part, edge8, ptr, dis);

  for (int l = 0; l < 3; ++l){
    if (l == 0){
      k_gemm <<<ceil_div(N_N, 64), 256, 0, stream>>>(node0, nullptr, 0,
                 nullptr, nullptr, nullptr, nullptr, nullptr, nullptr,
                 wt, dis, hb, N_N);
    } else {
      k_gemm <<<ceil_div(N_N, 64), 256, 0, stream>>>(nullptr, agg, 1,
                 bp, mean, rstd, ga + (l - 1) * HID, gw + (l - 1) * HID,
                 gb + (l - 1) * HID, wt + (size_t)l * HID * HID, dis, hb, N_N);
    }
    k_gather <<<ceil_div(N_N * 16, 256), 256, 0, stream>>>(ptr, edge8, hb, dis,
                 bias + l * HID, agg);
    k_gstat  <<<GSB, 256, 0, stream>>>(agg, gstart, gend, psum, psq,
                 ga + l * HID, mean, rstd, done + l);
  }
  k_out <<<ceil_div(N_N * 32, 256), 256, 0, stream>>>(agg, bp, mean, rstd,
             ga + 2 * HID, gw + 2 * HID, gb + 2 * HID, out);
}

// Round 12
// 543.987 us; speedup vs baseline: 1.3359x; 1.3359x over previous
//
#include <hip/hip_runtime.h>
#include <cstdint>

#define N_N 100000
#define N_E 1600000
#define HID 128
#define N_G 100
#define EPSF 1e-5f

// edge partition parameters
#define NB   256                      // partition blocks
#define EPB  ((N_E + NB - 1) / NB)    // 6250 edges per block
#define NBKT ((N_N + 255) >> 8)       // 391 buckets of 256 nodes (dst >> 8)
#define NBB  ((N_N + 255) / 256)      // 391 boundary blocks
#define NWT  ((3 * HID * HID) / 256)  // 192 Wt blocks

static inline int ceil_div(int a, int b){ return (a + b - 1) / b; }

typedef __attribute__((ext_vector_type(8))) short bf16x8;
typedef __attribute__((ext_vector_type(4))) float f32x4;

__device__ inline unsigned short f2bf(float f){
  unsigned int u = __float_as_uint(f);
  unsigned int r = u + 0x7fffu + ((u >> 16) & 1u);   // round-to-nearest-even
  return (unsigned short)(r >> 16);
}
// 8 packed bf16 (uint4) -> acc[0..7] += nv * val
__device__ inline void fma8(float* acc, float nv, uint4 u){
  acc[0] += nv * __uint_as_float(u.x << 16);
  acc[1] += nv * __uint_as_float(u.x & 0xffff0000u);
  acc[2] += nv * __uint_as_float(u.y << 16);
  acc[3] += nv * __uint_as_float(u.y & 0xffff0000u);
  acc[4] += nv * __uint_as_float(u.z << 16);
  acc[5] += nv * __uint_as_float(u.z & 0xffff0000u);
  acc[6] += nv * __uint_as_float(u.w << 16);
  acc[7] += nv * __uint_as_float(u.w & 0xffff0000u);
}

// ---- mega-pre: [0,NB) dst-histogram | [NB,NB+NBB) graph boundaries |
//      [NB+NBB, +NWT) W->bf16 transpose. All independent.
__global__ __launch_bounds__(256) void k_pre(const int* __restrict__ dst,
                                             int* __restrict__ counts,
                                             const int* __restrict__ bp,
                                             int* __restrict__ gstart,
                                             int* __restrict__ gend,
                                             const float* __restrict__ W,
                                             unsigned short* __restrict__ Wt){
  int t = threadIdx.x, blk = blockIdx.x;
  if (blk < NB){
    __shared__ int h[NBKT];
    for (int i = t; i < NBKT; i += 256) h[i] = 0;
    __syncthreads();
    int e0 = blk * EPB, e1 = min(e0 + EPB, N_E);
    for (int e = e0 + t; e < e1; e += 256)
      atomicAdd(&h[dst[e] >> 8], 1);
    __syncthreads();
    for (int i = t; i < NBKT; i += 256) counts[i * NB + blk] = h[i];
  } else if (blk < NB + NBB){
    // boundary detect on sorted bp; gap-fills empty graph ids (no init pass)
    int i = (blk - NB) * 256 + t;
    if (i >= N_N) return;
    int g = bp[i];
    if (i == 0){
      gstart[g] = 0;
      for (int gg = 0; gg < g; ++gg){ gstart[gg] = 0; gend[gg] = 0; }
    } else {
      int pg = bp[i - 1];
      if (pg != g){
        gend[pg] = i; gstart[g] = i;
        for (int gg = pg + 1; gg < g; ++gg){ gstart[gg] = i; gend[gg] = i; }
      }
    }
    if (i == N_N - 1){
      gend[g] = N_N;
      for (int gg = g + 1; gg < N_G; ++gg){ gstart[gg] = N_N; gend[gg] = N_N; }
    }
  } else {
    int j = (blk - NB - NBB) * 256 + t;
    int l = j >> 14;            // 128*128 = 16384 per layer
    int r = j & 16383;
    int n = r >> 7, k = r & 127;
    Wt[j] = f2bf(W[l * HID * HID + k * HID + n]);
  }
}

// block-local exclusive scan; bsum gets RAW block totals (no scanB pass)
__global__ __launch_bounds__(256) void k_scanA(int* __restrict__ data,
                                               int* __restrict__ bsum, int n){
  __shared__ int s[256];
  int t = threadIdx.x;
  int i = blockIdx.x * 256 + t;
  int v = (i < n) ? data[i] : 0;
  s[t] = v; __syncthreads();
  #pragma unroll
  for (int off = 1; off < 256; off <<= 1){
    int tmp = (t >= off) ? s[t - off] : 0;
    __syncthreads();
    s[t] += tmp;
    __syncthreads();
  }
  if (i < n) data[i] = s[t] - v;
  if (t == 255) bsum[blockIdx.x] = s[255];
}

// Pass 2: partition edges into buckets. Scans the 391 raw bsum totals in LDS
// (replaces the scanB launch), then ranks via LDS atomics.
__global__ __launch_bounds__(256) void k_part(const int* __restrict__ src,
                                              const int* __restrict__ dst,
                                              const float* __restrict__ w,
                                              const int* __restrict__ coff,
                                              const int* __restrict__ bsum,
                                              int2* __restrict__ part){
  __shared__ int off[NBKT];
  __shared__ int sb[512];
  int t = threadIdx.x, blk = blockIdx.x;
  sb[t]       = (t < NBKT)       ? bsum[t]       : 0;
  sb[t + 256] = (t + 256 < NBKT) ? bsum[t + 256] : 0;
  __syncthreads();
  #pragma unroll
  for (int o = 1; o < 256; o <<= 1){
    int a  = (t >= o) ? sb[t - o] : 0;
    int b2 = (t >= o) ? sb[256 + t - o] : 0;
    __syncthreads();
    sb[t] += a; sb[256 + t] += b2;
    __syncthreads();
  }
  int tot0 = sb[255];
  sb[256 + t] += tot0;            // no hazard: upper writes don't touch sb[255]
  __syncthreads();                // sb[0..510] = inclusive scan of bsum
  for (int i = t; i < NBKT; i += 256)
    off[i] = coff[i * NB + blk] + (i == 0 ? 0 : sb[i - 1]);
  __syncthreads();
  int e0 = blk * EPB, e1 = min(e0 + EPB, N_E);
  for (int e = e0 + t; e < e1; e += 256){
    int d = dst[e];
    int pos = atomicAdd(&off[d >> 8], 1);
    part[pos] = make_int2(src[e] | ((d & 255) << 24), __float_as_int(w[e]));
  }
}

// Pass 3: per-bucket fine CSR. Computes its own bsum prefix S(b) by masked
// block-reduce. Weighted degree -> dis; writes ptr; PRE-MULTIPLIES edge
// weight by dis[dst]. (dis[src] is folded into Hb at gemm.)
__global__ __launch_bounds__(256) void k_csr(const int* __restrict__ coff,
                                             const int* __restrict__ bsum,
                                             const int2* __restrict__ part,
                                             int2* __restrict__ edge8,
                                             int* __restrict__ ptr,
                                             float* __restrict__ dis){
  __shared__ int h[256];
  __shared__ int c[256];
  __shared__ float wsum[256];
  __shared__ int s[256];
  int t = threadIdx.x, b = blockIdx.x;
  // S(b) = sum_{j<b} bsum[j] via masked reduce
  int acc = 0;
  if (t < b) acc += bsum[t];
  if (t + 256 < b) acc += bsum[t + 256];
  s[t] = acc; __syncthreads();
  #pragma unroll
  for (int o = 128; o >= 1; o >>= 1){
    if (t < o) s[t] += s[t + o];
    __syncthreads();
  }
  int Sb = s[0];
  int base  = coff[b * NB] + Sb;
  int base2 = (b + 1 < NBKT) ? coff[(b + 1) * NB] + Sb + bsum[b] : N_E;
  h[t] = 0; c[t] = 0; wsum[t] = 0.f;
  __syncthreads();
  for (int e = base + t; e < base2; e += 256){
    int2 v = part[e];
    int local = ((unsigned int)v.x) >> 24;
    atomicAdd(&h[local], 1);
    atomicAdd(&wsum[local], __int_as_float(v.y));
  }
  __syncthreads();
  // exclusive scan of h
  int v0 = h[t];
  s[t] = v0; __syncthreads();
  #pragma unroll
  for (int off = 1; off < 256; off <<= 1){
    int tmp = (t >= off) ? s[t - off] : 0;
    __syncthreads();
    s[t] += tmp;
    __syncthreads();
  }
  int mybase = base + s[t] - v0;
  int node = (b << 8) + t;
  float dv = rsqrtf(1.0f + wsum[t]);
  if (node < N_N){
    ptr[node] = mybase;
    dis[node] = dv;
  }
  if (b == NBKT - 1 && t == 0) ptr[N_N] = N_E;
  h[t] = mybase;              // repurpose h as scatter base (own slot only)
  __syncthreads();
  wsum[t] = dv;               // repurpose wsum as dis[dst] for the scatter
  __syncthreads();
  for (int e = base + t; e < base2; e += 256){
    int2 v = part[e];
    int local = ((unsigned int)v.x) >> 24;
    int pos = h[local] + atomicAdd(&c[local], 1);
    edge8[pos] = make_int2(v.x & 0x00ffffff,
                           __float_as_int(__int_as_float(v.y) * wsum[local]));
  }
}

// ---------------- GEMM via MFMA, optional fused GraphNorm+ReLU on input ------
// fused=0: A row = X[gr]. fused=1: A row = relu(gw*(agg-al*mean)*rstd+gb).
// Epilogue: rows scaled by dis[row] (folds old k_ne into Hb), C staged as
// bf16 in LDS (lA reused), coalesced uint4 stores.
__global__ __launch_bounds__(256) void k_gemm(const float* __restrict__ X,
                                              const float* __restrict__ agg,
                                              int fused,
                                              const int* __restrict__ bp,
                                              const float* __restrict__ mean,
                                              const float* __restrict__ rstd,
                                              const float* __restrict__ alpha,
                                              const float* __restrict__ gwv,
                                              const float* __restrict__ gbv,
                                              const unsigned short* __restrict__ Wt,
                                              const float* __restrict__ dis,
                                              unsigned short* __restrict__ Hb, int nrows){
  __shared__ unsigned short lA[64 * 136];
  __shared__ unsigned short lB[128 * 136];
  int tid = threadIdx.x;
  int row0 = blockIdx.x * 64;

  #pragma unroll
  for (int i = 0; i < 8; ++i){
    int c = tid + i * 256;
    int r = c >> 4, cc = c & 15;
    *(uint4*)&lB[r * 136 + cc * 8] = ((const uint4*)Wt)[c];
  }
  #pragma unroll
  for (int i = 0; i < 8; ++i){
    int c = tid + i * 256;
    int r = c >> 5, cc = c & 31;
    int gr = row0 + r;
    float4 v = make_float4(0.f, 0.f, 0.f, 0.f);
    if (gr < nrows){
      if (!fused){
        v = *(const float4*)(X + (size_t)gr * HID + cc * 4);
      } else {
        int g = bp[gr];
        float4 a  = *(const float4*)(agg  + (size_t)gr * HID + cc * 4);
        float4 m  = *(const float4*)(mean + g * HID + cc * 4);
        float4 rs = *(const float4*)(rstd + g * HID + cc * 4);
        float4 al = *(const float4*)(alpha + cc * 4);
        float4 wv = *(const float4*)(gwv + cc * 4);
        float4 bv = *(const float4*)(gbv + cc * 4);
        v.x = fmaxf(wv.x * (a.x - al.x * m.x) * rs.x + bv.x, 0.f);
        v.y = fmaxf(wv.y * (a.y - al.y * m.y) * rs.y + bv.y, 0.f);
        v.z = fmaxf(wv.z * (a.z - al.z * m.z) * rs.z + bv.z, 0.f);
        v.w = fmaxf(wv.w * (a.w - al.w * m.w) * rs.w + bv.w, 0.f);
      }
    }
    unsigned short pk[4] = {f2bf(v.x), f2bf(v.y), f2bf(v.z), f2bf(v.w)};
    *(uint2*)&lA[r * 136 + cc * 4] = *(const uint2*)pk;
  }
  __syncthreads();

  int wave = tid >> 6;
  int lane = tid & 63;
  int l16 = lane & 15;
  int quad = lane >> 4;
  int am = wave * 16 + l16;

  bf16x8 afr[4];
  #pragma unroll
  for (int kc = 0; kc < 4; ++kc)
    afr[kc] = *(const bf16x8*)&lA[am * 136 + kc * 32 + quad * 8];

  f32x4 accs[8];
  #pragma unroll
  for (int nt = 0; nt < 8; ++nt){
    f32x4 acc = {0.f, 0.f, 0.f, 0.f};
    int bn = nt * 16 + l16;
    #pragma unroll
    for (int kc = 0; kc < 4; ++kc){
      bf16x8 bfr = *(const bf16x8*)&lB[bn * 136 + kc * 32 + quad * 8];
      acc = __builtin_amdgcn_mfma_f32_16x16x32_bf16(afr[kc], bfr, acc, 0, 0, 0);
    }
    accs[nt] = acc;
  }

  int crow = wave * 16 + quad * 4;
  float ds[4];
  #pragma unroll
  for (int r = 0; r < 4; ++r){
    int grr = row0 + crow + r;
    ds[r] = (grr < nrows) ? dis[grr] : 0.f;
  }

  // all afr reads from lA are done (pre-loop, barrier-ordered) -> reuse lA for C
  __syncthreads();
  #pragma unroll
  for (int nt = 0; nt < 8; ++nt){
    int col = nt * 16 + l16;
    #pragma unroll
    for (int r = 0; r < 4; ++r)
      lA[(crow + r) * 136 + col] = f2bf(accs[nt][r] * ds[r]);
  }
  __syncthreads();
  #pragma unroll
  for (int i = 0; i < 4; ++i){
    int idx = i * 256 + tid;            // 0..1023 = 64 rows x 16 uint4
    int row = idx >> 4, c8 = idx & 15;
    int gr = row0 + row;
    if (gr < nrows)
      *(uint4*)&Hb[(size_t)gr * HID + c8 * 8] = *(const uint4*)&lA[row * 136 + c8 * 8];
  }
}

// ---- gather aggregation: 16 lanes/node, unroll x4 (plain, proven 65us form) --
// Hb rows pre-scaled by dis[src]; edge weight pre-scaled by dis[dst];
// self term multiplier = dis[node] (dis^2 * h_orig = dis * h_scaled).
__global__ __launch_bounds__(256) void k_gather(const int* __restrict__ ptr,
                                                const int2* __restrict__ edge8,
                                                const unsigned short* __restrict__ Hb,
                                                const float* __restrict__ dis,
                                                const float* __restrict__ bias,
                                                float* __restrict__ agg){
  int t = blockIdx.x * 256 + threadIdx.x;
  int node = t >> 4;
  if (node >= N_N) return;
  int lane = t & 15;                        // 8 features (16B) per lane
  const uint4* h16 = (const uint4*)Hb;      // 16 uint4 per row
  float ns = dis[node];
  uint4 hu = h16[(size_t)node * 16 + lane];
  float4 b0 = ((const float4*)bias)[lane * 2];
  float4 b1 = ((const float4*)bias)[lane * 2 + 1];
  float acc[8] = {b0.x, b0.y, b0.z, b0.w, b1.x, b1.y, b1.z, b1.w};
  fma8(acc, ns, hu);

  int e0 = ptr[node], e1 = ptr[node + 1];
  int e = e0;
  for (; e + 4 <= e1; e += 4){
    int2 ev0 = edge8[e + 0];
    int2 ev1 = edge8[e + 1];
    int2 ev2 = edge8[e + 2];
    int2 ev3 = edge8[e + 3];
    uint4 r0 = h16[(size_t)ev0.x * 16 + lane];
    uint4 r1 = h16[(size_t)ev1.x * 16 + lane];
    uint4 r2 = h16[(size_t)ev2.x * 16 + lane];
    uint4 r3 = h16[(size_t)ev3.x * 16 + lane];
    fma8(acc, __int_as_float(ev0.y), r0);
    fma8(acc, __int_as_float(ev1.y), r1);
    fma8(acc, __int_as_float(ev2.y), r2);
    fma8(acc, __int_as_float(ev3.y), r3);
  }
  for (; e < e1; ++e){
    int2 ev = edge8[e];
    uint4 r0 = h16[(size_t)ev.x * 16 + lane];
    fma8(acc, __int_as_float(ev.y), r0);
  }
  float4* ap = (float4*)(agg + (size_t)node * HID + lane * 8);
  ap[0] = make_float4(acc[0], acc[1], acc[2], acc[3]);
  ap[1] = make_float4(acc[4], acc[5], acc[6], acc[7]);
}

// ---------------- GraphNorm: atomic-free two-phase reduction ----------------
// Phase 1: block (g, chunk c of 8) reduces its row range -> distinct psum slot.
__global__ __launch_bounds__(256) void k_gstat(const float* __restrict__ agg,
                                               const int* __restrict__ gstart,
                                               const int* __restrict__ gend,
                                               float* __restrict__ psum,
                                               float* __restrict__ psq){
  __shared__ float ls[256], lq[256];
  int g = blockIdx.x >> 3, c = blockIdx.x & 7;
  int s = gstart[g], e = gend[g];
  int len = e - s;
  int r0 = s + ((len * c) >> 3);
  int r1 = s + ((len * (c + 1)) >> 3);
  int f = threadIdx.x & 127, rr = threadIdx.x >> 7;
  float sm = 0.f, sq = 0.f;
  for (int r = r0 + rr; r < r1; r += 2){
    float v = agg[(size_t)r * HID + f];
    sm += v; sq += v * v;
  }
  ls[threadIdx.x] = sm; lq[threadIdx.x] = sq;
  __syncthreads();
  if (rr == 0){
    psum[(size_t)blockIdx.x * HID + f] = ls[f] + ls[f + 128];
    psq [(size_t)blockIdx.x * HID + f] = lq[f] + lq[f + 128];
  }
}

// Phase 2: fold 8 chunk-partials, compute mean/rstd. No atomics anywhere.
__global__ void k_finstat(const float* __restrict__ psum, const float* __restrict__ psq,
                          const int* __restrict__ gstart, const int* __restrict__ gend,
                          const float* __restrict__ alpha,
                          float* __restrict__ mean, float* __restrict__ rstd){
  int i = blockIdx.x * 256 + threadIdx.x;
  if (i >= N_G * HID) return;
  int g = i >> 7, f = i & (HID - 1);
  float c = (float)(gend[g] - gstart[g]);
  float inv = c > 0.f ? 1.0f / c : 0.f;
  float sm = 0.f, sq = 0.f;
  #pragma unroll
  for (int k = 0; k < 8; ++k){
    sm += psum[(size_t)(g * 8 + k) * HID + f];
    sq += psq [(size_t)(g * 8 + k) * HID + f];
  }
  float m = sm * inv;
  float ex2 = sq * inv;
  float al = alpha[f];
  float var = ex2 - m * m * al * (2.0f - al);
  mean[i] = m;
  rstd[i] = rsqrtf(var + EPSF);
}

__global__ void k_out(const float* __restrict__ agg, const int* __restrict__ bp,
                      const float* __restrict__ mean, const float* __restrict__ rstd,
                      const float* __restrict__ alpha, const float* __restrict__ gw,
                      const float* __restrict__ gb, float* __restrict__ out){
  int idx = blockIdx.x * 256 + threadIdx.x;
  if (idx >= N_N * 32) return;
  int i = idx >> 5, q = idx & 31;
  int g = bp[i];
  float4 a  = ((const float4*)agg)[idx];
  float4 m  = ((const float4*)mean)[g * 32 + q];
  float4 r  = ((const float4*)rstd)[g * 32 + q];
  float4 al = ((const float4*)alpha)[q];
  float4 wv = ((const float4*)gw)[q];
  float4 bv = ((const float4*)gb)[q];
  float4 o;
  o.x = fmaxf(wv.x * (a.x - al.x * m.x) * r.x + bv.x, 0.f);
  o.y = fmaxf(wv.y * (a.y - al.y * m.y) * r.y + bv.y, 0.f);
  o.z = fmaxf(wv.z * (a.z - al.z * m.z) * r.z + bv.z, 0.f);
  o.w = fmaxf(wv.w * (a.w - al.w * m.w) * r.w + bv.w, 0.f);
  ((float4*)out)[idx] = o;
}

// ---------------- launch ----------------

extern "C" void kernel_launch(void* const* d_in, const int* in_sizes, int n_in,
                              void* d_out, int out_size, void* d_ws, size_t ws_size,
                              hipStream_t stream){
  const float* node0 = (const float*)d_in[0];
  const int*   eidx  = (const int*)d_in[1];
  const float* eattr = (const float*)d_in[2];
  const int*   bp    = (const int*)d_in[3];
  const float* W     = (const float*)d_in[4];
  const float* bias  = (const float*)d_in[5];
  const float* gw    = (const float*)d_in[6];
  const float* gb    = (const float*)d_in[7];
  const float* ga    = (const float*)d_in[8];
  float* out = (float*)d_out;
  const int* src = eidx;
  const int* dst = eidx + N_E;

  char* p = (char*)d_ws;
  auto carve = [&](size_t nbytes) -> char* {
    char* q = p; p += (nbytes + 255) & ~(size_t)255; return q;
  };
  float* dis    = (float*)carve((size_t)N_N * 4);
  int*   gstart = (int*)  carve((size_t)N_G * 4);
  int*   gend   = (int*)  carve((size_t)N_G * 4);
  int*   coff   = (int*)  carve((size_t)NBKT * NB * 4);
  int*   bsum   = (int*)  carve((size_t)512 * 4);
  int*   ptr    = (int*)  carve((size_t)(N_N + 1) * 4);
  int2*  edge8  = (int2*) carve((size_t)N_E * 8);
  unsigned short* hb = (unsigned short*)carve((size_t)N_N * HID * 2);
  unsigned short* wt = (unsigned short*)carve((size_t)3 * HID * HID * 2);
  float* agg    = (float*)carve((size_t)N_N * HID * 4);
  float* mean   = (float*)carve((size_t)N_G * HID * 4);
  float* rstd   = (float*)carve((size_t)N_G * HID * 4);
  float* psum   = (float*)carve((size_t)N_G * 8 * HID * 4);
  float* psq    = (float*)carve((size_t)N_G * 8 * HID * 4);
  // bucket-partitioned edges alias agg (dead until first k_gather; 12.8MB < 51.2MB)
  int2*  part   = (int2*)agg;

  int nscan = NBKT * NB;                       // 100096
  int nscan_blocks = ceil_div(nscan, 256);     // 391 == NBKT

  k_pre  <<<NB + NBB + NWT, 256, 0, stream>>>(dst, coff, bp, gstart, gend, W, wt);
  k_scanA<<<nscan_blocks, 256, 0, stream>>>(coff, bsum, nscan);
  k_part <<<NB, 256, 0, stream>>>(src, dst, eattr, coff, bsum, part);
  k_csr  <<<NBKT, 256, 0, stream>>>(coff, bsum, part, edge8, ptr, dis);

  for (int l = 0; l < 3; ++l){
    if (l == 0){
      k_gemm <<<ceil_div(N_N, 64), 256, 0, stream>>>(node0, nullptr, 0,
                 nullptr, nullptr, nullptr, nullptr, nullptr, nullptr,
                 wt, dis, hb, N_N);
    } else {
      k_gemm <<<ceil_div(N_N, 64), 256, 0, stream>>>(nullptr, agg, 1,
                 bp, mean, rstd, ga + (l - 1) * HID, gw + (l - 1) * HID,
                 gb + (l - 1) * HID, wt + (size_t)l * HID * HID, dis, hb, N_N);
    }
    k_gather <<<ceil_div(N_N * 16, 256), 256, 0, stream>>>(ptr, edge8, hb, dis,
                 bias + l * HID, agg);
    k_gstat  <<<N_G * 8, 256, 0, stream>>>(agg, gstart, gend, psum, psq);
    k_finstat<<<ceil_div(N_G * HID, 256), 256, 0, stream>>>(psum, psq, gstart, gend,
                 ga + l * HID, mean, rstd);
  }
  k_out <<<ceil_div(N_N * 32, 256), 256, 0, stream>>>(agg, bp, mean, rstd,
             ga + 2 * HID, gw + 2 * HID, gb + 2 * HID, out);
}